// Round 7
// baseline (10850.600 us; speedup 1.0000x reference)
//
#include <hip/hip_runtime.h>
#include <hip/hip_bf16.h>
#include <cstddef>

typedef _Float16 f16;
typedef f16 f16x8 __attribute__((ext_vector_type(8)));
typedef float f32x4 __attribute__((ext_vector_type(4)));

#define NNODES 10000
#define NEDGES 320000

// ---------------------------------------------------------------------------
// Pack W [Nout][K] (fp32, row-major) into MFMA-B fragment-linear fp16:
// P[((ks*NB + nb)*64 + lane)*8 + i] = W[nb*16 + (lane&15)][ks*32 + 8*(lane>>4) + i]
// ---------------------------------------------------------------------------
__global__ void pack_b(const float* __restrict__ W, f16* __restrict__ P,
                       int Nout, int K) {
    int idx = blockIdx.x * 256 + threadIdx.x;
    int total = Nout * K;
    if (idx >= total) return;
    int i = idx & 7;
    int l = (idx >> 3) & 63;
    int rest = idx >> 9;
    int NB = Nout >> 4;
    int nb = rest % NB;
    int ks = rest / NB;
    int k = ks * 32 + ((l >> 4) << 3) + i;
    int n = nb * 16 + (l & 15);
    P[idx] = (f16)W[(size_t)n * K + k];
}

// ---------------------------------------------------------------------------
// Generic C = A @ W^T + bias. AMODE: 0 = fp32 A (convert), 1 = f16 A.
// OMODE: 0 = f32 out, 1 = f16 out, 2 = f32 out + f16 shadow copy (C2).
// ---------------------------------------------------------------------------
template <int AMODE, int OMODE>
__global__ void gemm_bias(const void* __restrict__ A_, const f16* __restrict__ P,
                          const float* __restrict__ bias, void* __restrict__ C_,
                          f16* __restrict__ C2, int M, int Nout, int K) {
    const int lane = threadIdx.x & 63, wave = threadIdx.x >> 6;
    const int wm = wave >> 1, wn = wave & 1;
    const int rb = blockIdx.x * 64 + wm * 32;
    const int cb = blockIdx.y * 64 + wn * 32;
    const int NB = Nout >> 4;
    const int kl = (lane >> 4) << 3;
    int r0 = rb + (lane & 15);
    int r1 = r0 + 16;
    int rc0 = r0 < M ? r0 : M - 1;
    int rc1 = r1 < M ? r1 : M - 1;
    f32x4 acc[2][2] = {};
    for (int ks = 0; ks < (K >> 5); ++ks) {
        int kb = ks * 32 + kl;
        f16x8 a0, a1;
        if constexpr (AMODE == 1) {
            const f16* A = (const f16*)A_;
            a0 = *(const f16x8*)(A + (size_t)rc0 * K + kb);
            a1 = *(const f16x8*)(A + (size_t)rc1 * K + kb);
        } else {
            const float* A = (const float*)A_;
            const float* p0 = A + (size_t)rc0 * K + kb;
            const float* p1 = A + (size_t)rc1 * K + kb;
#pragma unroll
            for (int i = 0; i < 8; ++i) { a0[i] = (f16)p0[i]; a1[i] = (f16)p1[i]; }
        }
#pragma unroll
        for (int nf = 0; nf < 2; ++nf) {
            int nb = (cb >> 4) + nf;
            f16x8 b = *(const f16x8*)(P + (((size_t)ks * NB + nb) * 64 + lane) * 8);
            acc[0][nf] = __builtin_amdgcn_mfma_f32_16x16x32_f16(a0, b, acc[0][nf], 0, 0, 0);
            acc[1][nf] = __builtin_amdgcn_mfma_f32_16x16x32_f16(a1, b, acc[1][nf], 0, 0, 0);
        }
    }
#pragma unroll
    for (int mf = 0; mf < 2; ++mf)
#pragma unroll
        for (int nf = 0; nf < 2; ++nf)
#pragma unroll
            for (int reg = 0; reg < 4; ++reg) {
                int row = rb + mf * 16 + ((lane >> 4) << 2) + reg;
                int col = cb + nf * 16 + (lane & 15);
                if (row < M) {
                    float v = acc[mf][nf][reg] + bias[col];
                    if constexpr (OMODE == 0) {
                        ((float*)C_)[(size_t)row * Nout + col] = v;
                    } else if constexpr (OMODE == 1) {
                        ((f16*)C_)[(size_t)row * Nout + col] = (f16)v;
                    } else {
                        ((float*)C_)[(size_t)row * Nout + col] = v;
                        C2[(size_t)row * Nout + col] = (f16)v;
                    }
                }
            }
}

// fast activations (error ~1e-6, negligible vs f16 pipeline error)
__device__ inline float sigmoidf_(float x) {
    return __fdividef(1.f, 1.f + __expf(-x));
}
__device__ inline float tanhf_(float x) {
    x = fminf(fmaxf(x, -15.f), 15.f);
    float t = __expf(-2.f * x);
    return __fdividef(1.f - t, 1.f + t);
}

// ---------------------------------------------------------------------------
// Fused edge GRU v4, IN-PLACE on uef. Block = 2 consecutive 64-edge tiles,
// software-pipelined: tile t+1's staging (src/uef/dst rows -> 48 VGPRs) is
// issued mid-way through tile t's MFMA phases, so HBM latency hides under
// compute. 512 thr = 8 waves, one 32-col group each, mf=4 row-frags.
// LDS ~66 KB: lds_x reused (src half -> dst half), lds_h lives to epilogue.
// Register budget: 128 acc + 48 staging + ~45 misc ~= 220 < 256 (2 w/SIMD).
// acc sets: 0 = ir+hr, 1 = iz+hz, 2 = inn, 3 = hn
// ---------------------------------------------------------------------------
__global__ __launch_bounds__(512, 2) void edge_gru(
        const f16* __restrict__ unf16, f16* __restrict__ uef,
        const int* __restrict__ src, const int* __restrict__ dst,
        const f16* __restrict__ Pih, const f16* __restrict__ Phh,
        const float* __restrict__ bih, const float* __restrict__ bhh) {
    __shared__ int s_idx[2][128];      // per tile: [0..63]=src, [64..127]=dst
    __shared__ char lds_x[64 * 512];   // xe half-tile (src, then dst), swizzled
    __shared__ char lds_h[64 * 512];   // uef tile, swizzled
    const int t = threadIdx.x;
    const int e_base = blockIdx.x * 128;
    if (t < 128) {
        int e = e_base + (t & 63);
        s_idx[0][t] = (t < 64) ? src[e] : dst[e];
    } else if (t < 256) {
        int tt = t - 128;
        int e = e_base + 64 + (tt & 63);
        s_idx[1][tt] = (tt < 64) ? src[e] : dst[e];
    }
    __syncthreads();

    const int lane = t & 63, wn = t >> 6;   // 8 waves, one col-group each
    const int cb = wn * 32;
    const int nb0 = wn * 2;
    const int klb = (lane >> 4) << 4;       // byte offset of lane's k-slice
    const int srow = t >> 5;                // staging row base (stride 16)
    const int sseg = t & 31;                // staging 16B segment

    // prologue: issue tile-0 staging loads
    f16x8 sreg[4], hreg[4], dreg[4];
#pragma unroll
    for (int i = 0; i < 4; ++i) {
        int row = srow + i * 16;
        sreg[i] = *(const f16x8*)(unf16 + (size_t)s_idx[0][row] * 256 + sseg * 8);
        hreg[i] = *(const f16x8*)(uef + (size_t)(e_base + row) * 256 + sseg * 8);
        dreg[i] = *(const f16x8*)(unf16 + (size_t)s_idx[0][64 + row] * 256 + sseg * 8);
    }

    for (int tt = 0; tt < 2; ++tt) {
        const int e0 = e_base + tt * 64;
        __syncthreads();   // previous iteration's LDS readers done
#pragma unroll
        for (int i = 0; i < 4; ++i) {
            int row = srow + i * 16;
            int sw = (row * 512 + sseg * 16) ^ ((row & 7) << 4);
            *(f16x8*)(lds_x + sw) = sreg[i];
            *(f16x8*)(lds_h + sw) = hreg[i];
        }
        __syncthreads();

        f32x4 acc[4][4][2] = {};            // [gateset][mf][nf]
        // phase 1a: xe(src half) @ Wih^T, ks = 0..7
#pragma unroll
        for (int ks = 0; ks < 8; ++ks) {
            const int colb = ks * 64 + klb;
            f16x8 a[4];
#pragma unroll
            for (int mf = 0; mf < 4; ++mf) {
                int row = mf * 16 + (lane & 15);
                a[mf] = *(const f16x8*)(lds_x + ((row * 512 + colb) ^ ((row & 7) << 4)));
            }
#pragma unroll
            for (int g = 0; g < 3; ++g) {
                const f16* Pg = Pih + (size_t)g * (512 * 256);
#pragma unroll
                for (int nf = 0; nf < 2; ++nf) {
                    f16x8 b = *(const f16x8*)(Pg + (((size_t)ks * 16 + nb0 + nf) * 64 + lane) * 8);
#pragma unroll
                    for (int mf = 0; mf < 4; ++mf)
                        acc[g][mf][nf] = __builtin_amdgcn_mfma_f32_16x16x32_f16(a[mf], b, acc[g][mf][nf], 0, 0, 0);
                }
            }
        }
        __syncthreads();   // all waves done reading src half
#pragma unroll
        for (int i = 0; i < 4; ++i) {
            int row = srow + i * 16;
            *(f16x8*)(lds_x + ((row * 512 + sseg * 16) ^ ((row & 7) << 4))) = dreg[i];
        }
        __syncthreads();
        // issue next tile's staging loads; latency hides under phases 1b/2
        if (tt == 0) {
#pragma unroll
            for (int i = 0; i < 4; ++i) {
                int row = srow + i * 16;
                sreg[i] = *(const f16x8*)(unf16 + (size_t)s_idx[1][row] * 256 + sseg * 8);
                hreg[i] = *(const f16x8*)(uef + (size_t)(e_base + 64 + row) * 256 + sseg * 8);
                dreg[i] = *(const f16x8*)(unf16 + (size_t)s_idx[1][64 + row] * 256 + sseg * 8);
            }
        }
        // phase 1b: xe(dst half) @ Wih^T, ks = 8..15
#pragma unroll
        for (int ks = 8; ks < 16; ++ks) {
            const int colb = (ks - 8) * 64 + klb;
            f16x8 a[4];
#pragma unroll
            for (int mf = 0; mf < 4; ++mf) {
                int row = mf * 16 + (lane & 15);
                a[mf] = *(const f16x8*)(lds_x + ((row * 512 + colb) ^ ((row & 7) << 4)));
            }
#pragma unroll
            for (int g = 0; g < 3; ++g) {
                const f16* Pg = Pih + (size_t)g * (512 * 256);
#pragma unroll
                for (int nf = 0; nf < 2; ++nf) {
                    f16x8 b = *(const f16x8*)(Pg + (((size_t)ks * 16 + nb0 + nf) * 64 + lane) * 8);
#pragma unroll
                    for (int mf = 0; mf < 4; ++mf)
                        acc[g][mf][nf] = __builtin_amdgcn_mfma_f32_16x16x32_f16(a[mf], b, acc[g][mf][nf], 0, 0, 0);
                }
            }
        }
        // phase 2: h @ Whh^T (K = 256, A = staged uef tile)
#pragma unroll
        for (int ks = 0; ks < 8; ++ks) {
            const int colb = ks * 64 + klb;
            f16x8 a[4];
#pragma unroll
            for (int mf = 0; mf < 4; ++mf) {
                int row = mf * 16 + (lane & 15);
                a[mf] = *(const f16x8*)(lds_h + ((row * 512 + colb) ^ ((row & 7) << 4)));
            }
#pragma unroll
            for (int g = 0; g < 3; ++g) {
                const f16* Pg = Phh + (size_t)g * (256 * 256);
                const int tgt = (g == 2) ? 3 : g;
#pragma unroll
                for (int nf = 0; nf < 2; ++nf) {
                    f16x8 b = *(const f16x8*)(Pg + (((size_t)ks * 16 + nb0 + nf) * 64 + lane) * 8);
#pragma unroll
                    for (int mf = 0; mf < 4; ++mf)
                        acc[tgt][mf][nf] = __builtin_amdgcn_mfma_f32_16x16x32_f16(a[mf], b, acc[tgt][mf][nf], 0, 0, 0);
                }
            }
        }
        // epilogue (h from lds_h; in-place global write is race-free)
#pragma unroll
        for (int nf = 0; nf < 2; ++nf) {
            const int j = cb + nf * 16 + (lane & 15);
            const float b_r = bih[j] + bhh[j];
            const float b_z = bih[256 + j] + bhh[256 + j];
            const float b_i = bih[512 + j];
            const float b_h = bhh[512 + j];
#pragma unroll
            for (int mf = 0; mf < 4; ++mf) {
                const int rloc = mf * 16 + ((lane >> 4) << 2);
#pragma unroll
                for (int reg = 0; reg < 4; ++reg) {
                    const int rr = rloc + reg;
                    float r = sigmoidf_(acc[0][mf][nf][reg] + b_r);
                    float z = sigmoidf_(acc[1][mf][nf][reg] + b_z);
                    float nn = tanhf_(acc[2][mf][nf][reg] + b_i + r * (acc[3][mf][nf][reg] + b_h));
                    float h = (float)*(const f16*)(lds_h + ((rr * 512 + j * 2) ^ ((rr & 7) << 4)));
                    uef[(size_t)(e0 + rr) * 256 + j] = (f16)((1.f - z) * nn + z * h);
                }
            }
        }
    }
}

// ---------------------------------------------------------------------------
// Fused node GRU, IN-PLACE on unf (fp32 state); also refreshes f16 shadow.
// Block: 64 nodes x 256 cols, 1024 threads, 16 waves.
// ---------------------------------------------------------------------------
__global__ __launch_bounds__(1024) void node_gru(
        const float* __restrict__ agg, float* __restrict__ unf,
        f16* __restrict__ unf16,
        const f16* __restrict__ Pih, const f16* __restrict__ Phh,
        const float* __restrict__ bih, const float* __restrict__ bhh, int M) {
    const int lane = threadIdx.x & 63, wave = threadIdx.x >> 6;
    const int wm = wave & 1, wn = wave >> 1;
    const int rb = blockIdx.x * 64 + wm * 32;
    const int cb = wn * 32;
    const int nb0 = wn * 2;
    const int kl = (lane >> 4) << 3;
    int r0 = rb + (lane & 15), r1 = r0 + 16;
    int rc0 = r0 < M ? r0 : M - 1;
    int rc1 = r1 < M ? r1 : M - 1;
    f32x4 acc[4][2][2] = {};
#pragma unroll
    for (int ks = 0; ks < 8; ++ks) {
        const float* p0 = agg + (size_t)rc0 * 256 + ks * 32 + kl;
        const float* p1 = agg + (size_t)rc1 * 256 + ks * 32 + kl;
        f16x8 a0, a1;
#pragma unroll
        for (int i = 0; i < 8; ++i) { a0[i] = (f16)p0[i]; a1[i] = (f16)p1[i]; }
#pragma unroll
        for (int g = 0; g < 3; ++g) {
            const f16* Pg = Pih + (size_t)g * (256 * 256);
#pragma unroll
            for (int nf = 0; nf < 2; ++nf) {
                f16x8 b = *(const f16x8*)(Pg + (((size_t)ks * 16 + nb0 + nf) * 64 + lane) * 8);
                acc[g][0][nf] = __builtin_amdgcn_mfma_f32_16x16x32_f16(a0, b, acc[g][0][nf], 0, 0, 0);
                acc[g][1][nf] = __builtin_amdgcn_mfma_f32_16x16x32_f16(a1, b, acc[g][1][nf], 0, 0, 0);
            }
        }
    }
#pragma unroll
    for (int ks = 0; ks < 8; ++ks) {
        const float* p0 = unf + (size_t)rc0 * 256 + ks * 32 + kl;
        const float* p1 = unf + (size_t)rc1 * 256 + ks * 32 + kl;
        f16x8 a0, a1;
#pragma unroll
        for (int i = 0; i < 8; ++i) { a0[i] = (f16)p0[i]; a1[i] = (f16)p1[i]; }
#pragma unroll
        for (int g = 0; g < 3; ++g) {
            const f16* Pg = Phh + (size_t)g * (256 * 256);
            const int tgt = (g == 2) ? 3 : g;
#pragma unroll
            for (int nf = 0; nf < 2; ++nf) {
                f16x8 b = *(const f16x8*)(Pg + (((size_t)ks * 16 + nb0 + nf) * 64 + lane) * 8);
                acc[tgt][0][nf] = __builtin_amdgcn_mfma_f32_16x16x32_f16(a0, b, acc[tgt][0][nf], 0, 0, 0);
                acc[tgt][1][nf] = __builtin_amdgcn_mfma_f32_16x16x32_f16(a1, b, acc[tgt][1][nf], 0, 0, 0);
            }
        }
    }
    __syncthreads();
#pragma unroll
    for (int mf = 0; mf < 2; ++mf) {
        const int row = rb + mf * 16 + ((lane >> 4) << 2);
#pragma unroll
        for (int nf = 0; nf < 2; ++nf) {
            const int j = cb + nf * 16 + (lane & 15);
            const float b_r = bih[j] + bhh[j];
            const float b_z = bih[256 + j] + bhh[256 + j];
            const float b_i = bih[512 + j];
            const float b_h = bhh[512 + j];
#pragma unroll
            for (int reg = 0; reg < 4; ++reg) {
                const int rr = row + reg;
                if (rr < M) {
                    float r = sigmoidf_(acc[0][mf][nf][reg] + b_r);
                    float z = sigmoidf_(acc[1][mf][nf][reg] + b_z);
                    float nn = tanhf_(acc[2][mf][nf][reg] + b_i + r * (acc[3][mf][nf][reg] + b_h));
                    float h = unf[(size_t)rr * 256 + j];     // own region only
                    float v = (1.f - z) * nn + z * h;
                    unf[(size_t)rr * 256 + j] = v;
                    unf16[(size_t)rr * 256 + j] = (f16)v;
                }
            }
        }
    }
}

// ---------------------------------------------------------------------------
// CSR build + aggregation (fp32 accumulate, fp32 store)
// ---------------------------------------------------------------------------
__global__ void hist_k(const int* __restrict__ dst, int* __restrict__ cnt, int E) {
    int e = blockIdx.x * 256 + threadIdx.x;
    if (e < E) atomicAdd(&cnt[dst[e]], 1);
}

__global__ void scan_k(const int* __restrict__ cnt, int* __restrict__ rowptr, int n) {
    __shared__ int s[1024];
    __shared__ int carry_s;
    if (threadIdx.x == 0) { carry_s = 0; rowptr[0] = 0; }
    __syncthreads();
    for (int base = 0; base < n; base += 1024) {
        int i = base + (int)threadIdx.x;
        int v = (i < n) ? cnt[i] : 0;
        s[threadIdx.x] = v;
        __syncthreads();
        for (int off = 1; off < 1024; off <<= 1) {
            int tv = (threadIdx.x >= (unsigned)off) ? s[threadIdx.x - off] : 0;
            __syncthreads();
            s[threadIdx.x] += tv;
            __syncthreads();
        }
        if (i < n) rowptr[i + 1] = carry_s + s[threadIdx.x];
        __syncthreads();
        if (threadIdx.x == 0) carry_s += s[1023];
        __syncthreads();
    }
}

__global__ void scatter_k(const int* __restrict__ dst, const int* __restrict__ rowptr,
                          int* __restrict__ cnt2, int* __restrict__ eidx, int E) {
    int e = blockIdx.x * 256 + threadIdx.x;
    if (e < E) {
        int d = dst[e];
        int p = rowptr[d] + atomicAdd(&cnt2[d], 1);
        eidx[p] = e;
    }
}

__global__ void aggregate_k(const f16* __restrict__ uef, const int* __restrict__ eidx,
                            const int* __restrict__ rowptr, float* __restrict__ agg) {
    const int n = blockIdx.x;
    const int c = threadIdx.x;  // 256 threads, one column each
    const int b = rowptr[n], e = rowptr[n + 1];
    float acc = 0.f;
    for (int j = b; j < e; ++j) acc += (float)uef[(size_t)eidx[j] * 256 + c];
    agg[(size_t)n * 256 + c] = acc;
}

// ---------------------------------------------------------------------------
extern "C" void kernel_launch(void* const* d_in, const int* in_sizes, int n_in,
                              void* d_out, int out_size, void* d_ws, size_t ws_size,
                              hipStream_t stream) {
    (void)in_sizes; (void)n_in; (void)out_size; (void)ws_size;
    const float* nf    = (const float*)d_in[0];
    const float* ef    = (const float*)d_in[1];
    const int*   src   = (const int*)d_in[2];
    const int*   dst   = (const int*)d_in[3];
    const float* Wne   = (const float*)d_in[4];
    const float* bne   = (const float*)d_in[5];
    const float* Wee   = (const float*)d_in[6];
    const float* bee   = (const float*)d_in[7];
    const float* Wih_e = (const float*)d_in[8];
    const float* Whh_e = (const float*)d_in[9];
    const float* bih_e = (const float*)d_in[10];
    const float* bhh_e = (const float*)d_in[11];
    const float* Wih_n = (const float*)d_in[12];
    const float* Whh_n = (const float*)d_in[13];
    const float* bih_n = (const float*)d_in[14];
    const float* bhh_n = (const float*)d_in[15];
    const float* Wnd   = (const float*)d_in[16];
    const float* bnd   = (const float*)d_in[17];
    const float* Wed   = (const float*)d_in[18];
    const float* bed   = (const float*)d_in[19];

    char* ws = (char*)d_ws;
    size_t off = 0;
    auto alloc = [&](size_t bytes) -> void* {
        void* p = ws + off;
        off += (bytes + 255) & ~(size_t)255;
        return p;
    };
    // total ~197 MB (well under the ~347 MB proven-working bound)
    f16*   uefA  = (f16*)alloc((size_t)NEDGES * 256 * 2);      // 163.8 MB
    float* unfA  = (float*)alloc((size_t)NNODES * 256 * 4);    // 10.2 MB
    f16*   unf16 = (f16*)alloc((size_t)NNODES * 256 * 2);      // 5.1 MB
    float* agg   = (float*)alloc((size_t)NNODES * 256 * 4);    // 10.2 MB
    f16*   Pih_e = (f16*)alloc((size_t)3 * 512 * 256 * 2);
    f16*   Phh_e = (f16*)alloc((size_t)3 * 256 * 256 * 2);
    f16*   Pih_n = (f16*)alloc((size_t)3 * 256 * 256 * 2);
    f16*   Phh_n = (f16*)alloc((size_t)3 * 256 * 256 * 2);
    f16*   Pne   = (f16*)alloc((size_t)256 * 128 * 2);
    f16*   Pee   = (f16*)alloc((size_t)256 * 64 * 2);
    f16*   Pnd   = (f16*)alloc((size_t)128 * 256 * 2);
    f16*   Ped   = (f16*)alloc((size_t)64 * 256 * 2);
    int* cnt    = (int*)alloc((size_t)NNODES * 4);
    int* cnt2   = (int*)alloc((size_t)NNODES * 4);
    int* rowptr = (int*)alloc((size_t)(NNODES + 1) * 4);
    int* eidx   = (int*)alloc((size_t)NEDGES * 4);

    hipMemsetAsync(cnt, 0, (size_t)NNODES * 4, stream);
    hipMemsetAsync(cnt2, 0, (size_t)NNODES * 4, stream);

    // pack weights
    for (int g = 0; g < 3; ++g) {
        pack_b<<<(256 * 512 + 255) / 256, 256, 0, stream>>>(Wih_e + (size_t)g * 256 * 512,
                                                            Pih_e + (size_t)g * 512 * 256, 256, 512);
        pack_b<<<(256 * 256 + 255) / 256, 256, 0, stream>>>(Whh_e + (size_t)g * 256 * 256,
                                                            Phh_e + (size_t)g * 256 * 256, 256, 256);
        pack_b<<<(256 * 256 + 255) / 256, 256, 0, stream>>>(Wih_n + (size_t)g * 256 * 256,
                                                            Pih_n + (size_t)g * 256 * 256, 256, 256);
        pack_b<<<(256 * 256 + 255) / 256, 256, 0, stream>>>(Whh_n + (size_t)g * 256 * 256,
                                                            Phh_n + (size_t)g * 256 * 256, 256, 256);
    }
    pack_b<<<(256 * 128 + 255) / 256, 256, 0, stream>>>(Wne, Pne, 256, 128);
    pack_b<<<(256 * 64 + 255) / 256, 256, 0, stream>>>(Wee, Pee, 256, 64);
    pack_b<<<(128 * 256 + 255) / 256, 256, 0, stream>>>(Wnd, Pnd, 128, 256);
    pack_b<<<(64 * 256 + 255) / 256, 256, 0, stream>>>(Wed, Ped, 64, 256);

    // CSR by dst
    hist_k<<<(NEDGES + 255) / 256, 256, 0, stream>>>(dst, cnt, NEDGES);
    scan_k<<<1, 1024, 0, stream>>>(cnt, rowptr, NNODES);
    scatter_k<<<(NEDGES + 255) / 256, 256, 0, stream>>>(dst, rowptr, cnt2, eidx, NEDGES);

    // encode (node encoder -> fp32 unf + f16 shadow; edge encoder -> f16 uef)
    gemm_bias<0, 2><<<dim3(157, 4), 256, 0, stream>>>(nf, Pne, bne, unfA, unf16, NNODES, 256, 128);
    gemm_bias<0, 1><<<dim3(5000, 4), 256, 0, stream>>>(ef, Pee, bee, uefA, nullptr, NEDGES, 256, 64);

    // message passing (both GRUs in-place)
    for (int it = 0; it < 3; ++it) {
        edge_gru<<<2500, 512, 0, stream>>>(unf16, uefA, src, dst, Pih_e, Phh_e, bih_e, bhh_e);
        aggregate_k<<<NNODES, 256, 0, stream>>>(uefA, eidx, rowptr, agg);
        node_gru<<<157, 1024, 0, stream>>>(agg, unfA, unf16, Pih_n, Phh_n, bih_n, bhh_n, NNODES);
    }

    // decode (node from fp32 unf; edge from f16 uef)
    gemm_bias<0, 0><<<dim3(157, 2), 256, 0, stream>>>(unfA, Pnd, bnd, d_out, nullptr, NNODES, 128, 256);
    gemm_bias<1, 0><<<dim3(5000, 1), 256, 0, stream>>>(uefA, Ped, bed,
                                                       (float*)d_out + (size_t)NNODES * 128, nullptr,
                                                       NEDGES, 64, 256);
}

// Round 8
// 3853.303 us; speedup vs baseline: 2.8159x; 2.8159x over previous
//
#include <hip/hip_runtime.h>
#include <hip/hip_bf16.h>
#include <cstddef>

typedef _Float16 f16;
typedef f16 f16x8 __attribute__((ext_vector_type(8)));
typedef float f32x4 __attribute__((ext_vector_type(4)));

#define NNODES 10000
#define NEDGES 320000

// ---------------------------------------------------------------------------
// Pack W [Nout][K] (fp32, row-major) into MFMA-B fragment-linear fp16:
// P[((ks*NB + nb)*64 + lane)*8 + i] = W[nb*16 + (lane&15)][ks*32 + 8*(lane>>4) + i]
// ---------------------------------------------------------------------------
__global__ void pack_b(const float* __restrict__ W, f16* __restrict__ P,
                       int Nout, int K) {
    int idx = blockIdx.x * 256 + threadIdx.x;
    int total = Nout * K;
    if (idx >= total) return;
    int i = idx & 7;
    int l = (idx >> 3) & 63;
    int rest = idx >> 9;
    int NB = Nout >> 4;
    int nb = rest % NB;
    int ks = rest / NB;
    int k = ks * 32 + ((l >> 4) << 3) + i;
    int n = nb * 16 + (l & 15);
    P[idx] = (f16)W[(size_t)n * K + k];
}

// ---------------------------------------------------------------------------
// Generic C = A @ W^T + bias. AMODE: 0 = fp32 A (convert), 1 = f16 A.
// OMODE: 0 = f32 out, 1 = f16 out, 2 = f32 out + f16 shadow copy (C2).
// ---------------------------------------------------------------------------
template <int AMODE, int OMODE>
__global__ void gemm_bias(const void* __restrict__ A_, const f16* __restrict__ P,
                          const float* __restrict__ bias, void* __restrict__ C_,
                          f16* __restrict__ C2, int M, int Nout, int K) {
    const int lane = threadIdx.x & 63, wave = threadIdx.x >> 6;
    const int wm = wave >> 1, wn = wave & 1;
    const int rb = blockIdx.x * 64 + wm * 32;
    const int cb = blockIdx.y * 64 + wn * 32;
    const int NB = Nout >> 4;
    const int kl = (lane >> 4) << 3;
    int r0 = rb + (lane & 15);
    int r1 = r0 + 16;
    int rc0 = r0 < M ? r0 : M - 1;
    int rc1 = r1 < M ? r1 : M - 1;
    f32x4 acc[2][2] = {};
    for (int ks = 0; ks < (K >> 5); ++ks) {
        int kb = ks * 32 + kl;
        f16x8 a0, a1;
        if constexpr (AMODE == 1) {
            const f16* A = (const f16*)A_;
            a0 = *(const f16x8*)(A + (size_t)rc0 * K + kb);
            a1 = *(const f16x8*)(A + (size_t)rc1 * K + kb);
        } else {
            const float* A = (const float*)A_;
            const float* p0 = A + (size_t)rc0 * K + kb;
            const float* p1 = A + (size_t)rc1 * K + kb;
#pragma unroll
            for (int i = 0; i < 8; ++i) { a0[i] = (f16)p0[i]; a1[i] = (f16)p1[i]; }
        }
#pragma unroll
        for (int nf = 0; nf < 2; ++nf) {
            int nb = (cb >> 4) + nf;
            f16x8 b = *(const f16x8*)(P + (((size_t)ks * NB + nb) * 64 + lane) * 8);
            acc[0][nf] = __builtin_amdgcn_mfma_f32_16x16x32_f16(a0, b, acc[0][nf], 0, 0, 0);
            acc[1][nf] = __builtin_amdgcn_mfma_f32_16x16x32_f16(a1, b, acc[1][nf], 0, 0, 0);
        }
    }
#pragma unroll
    for (int mf = 0; mf < 2; ++mf)
#pragma unroll
        for (int nf = 0; nf < 2; ++nf)
#pragma unroll
            for (int reg = 0; reg < 4; ++reg) {
                int row = rb + mf * 16 + ((lane >> 4) << 2) + reg;
                int col = cb + nf * 16 + (lane & 15);
                if (row < M) {
                    float v = acc[mf][nf][reg] + bias[col];
                    if constexpr (OMODE == 0) {
                        ((float*)C_)[(size_t)row * Nout + col] = v;
                    } else if constexpr (OMODE == 1) {
                        ((f16*)C_)[(size_t)row * Nout + col] = (f16)v;
                    } else {
                        ((float*)C_)[(size_t)row * Nout + col] = v;
                        C2[(size_t)row * Nout + col] = (f16)v;
                    }
                }
            }
}

// fast activations; tail-safe without clamps (inf handled by rcp -> 0)
__device__ inline float sigmoidf_(float x) {
    return __fdividef(1.f, 1.f + __expf(-x));
}
__device__ inline float tanhf_(float x) {
    float t = __expf(2.f * x);           // inf for large x is fine
    return 1.f - __fdividef(2.f, t + 1.f);
}

// ---------------------------------------------------------------------------
// Fused edge GRU (round-5 structure, proven 736us / no spill), IN-PLACE on
// uef. Block: 64 edges x 256 cols, 512 thr = 8 waves, one 32-col group each,
// mf=4 row-frags. xe (128 gathered unf16 rows) and uef rows staged once into
// swizzled LDS. Register envelope: 128 acc (AGPR) + ~120 arch = 248 <= 256.
// NEW vs round 5: B-weight loads use wave-uniform scalar base (readfirstlane)
// + compile-time offsets -> saddr-form loads, ~290 fewer VALU insts/wave.
// acc sets: 0 = ir+hr, 1 = iz+hz, 2 = inn, 3 = hn
// ---------------------------------------------------------------------------
__global__ __launch_bounds__(512, 2) void edge_gru(
        const f16* __restrict__ unf16, f16* __restrict__ uef,
        const int* __restrict__ src, const int* __restrict__ dst,
        const f16* __restrict__ Pih, const f16* __restrict__ Phh,
        const float* __restrict__ bih, const float* __restrict__ bhh) {
    __shared__ int s_idx[128];
    __shared__ char lds_x[128 * 512];   // xe tile: 128 rows x 512 B, swizzled
    __shared__ char lds_h[64 * 512];    // uef tile: 64 rows x 512 B, swizzled
    const int t = threadIdx.x;
    const int e0 = blockIdx.x * 64;
    if (t < 64) s_idx[t] = src[e0 + t];
    else if (t < 128) s_idx[t] = dst[e0 + t - 64];
    __syncthreads();
    // stage xe: 128 rows x 32 segs(16B) = 4096 segs / 512 thr = 8 iters
#pragma unroll
    for (int i = 0; i < 8; ++i) {
        int s = t + i * 512;
        int row = s >> 5, seg = s & 31;
        f16x8 v = *(const f16x8*)(unf16 + (size_t)s_idx[row] * 256 + seg * 8);
        *(f16x8*)(lds_x + ((row * 512 + seg * 16) ^ ((row & 7) << 4))) = v;
    }
    // stage uef: 64 rows x 32 segs = 2048 / 512 = 4 iters
#pragma unroll
    for (int i = 0; i < 4; ++i) {
        int s = t + i * 512;
        int row = s >> 5, seg = s & 31;
        f16x8 v = *(const f16x8*)(uef + (size_t)(e0 + row) * 256 + seg * 8);
        *(f16x8*)(lds_h + ((row * 512 + seg * 16) ^ ((row & 7) << 4))) = v;
    }
    __syncthreads();
    const int lane = t & 63;
    const int wn = __builtin_amdgcn_readfirstlane(t >> 6);  // wave-uniform scalar
    const int cb = wn * 32;
    const int klb = (lane >> 4) << 4;       // byte offset of lane's k-slice
    const int le8 = lane * 8;               // vector part of B offsets
    const f16* PihW = Pih + (size_t)(wn * 2) * 512;   // uniform base
    const f16* PhhW = Phh + (size_t)(wn * 2) * 512;   // uniform base
    f32x4 acc[4][4][2] = {};                // [gateset][mf][nf]
    // phase 1: xe @ Wih^T (K = 512; rows 0..63 = src half, 64..127 = dst half)
#pragma unroll
    for (int ks = 0; ks < 16; ++ks) {
        const int colb = (ks & 7) * 64 + klb;
        const int rbase = (ks < 8) ? 0 : 64;
        f16x8 a[4];
#pragma unroll
        for (int mf = 0; mf < 4; ++mf) {
            int row = rbase + mf * 16 + (lane & 15);
            a[mf] = *(const f16x8*)(lds_x + ((row * 512 + colb) ^ ((row & 7) << 4)));
        }
#pragma unroll
        for (int g = 0; g < 3; ++g) {
#pragma unroll
            for (int nf = 0; nf < 2; ++nf) {
                f16x8 b = *(const f16x8*)(PihW + (size_t)g * (512 * 256)
                                          + ks * 8192 + nf * 512 + le8);
#pragma unroll
                for (int mf = 0; mf < 4; ++mf)
                    acc[g][mf][nf] = __builtin_amdgcn_mfma_f32_16x16x32_f16(a[mf], b, acc[g][mf][nf], 0, 0, 0);
            }
        }
    }
    // phase 2: h @ Whh^T (K = 256, A = staged uef tile)
#pragma unroll
    for (int ks = 0; ks < 8; ++ks) {
        const int colb = ks * 64 + klb;
        f16x8 a[4];
#pragma unroll
        for (int mf = 0; mf < 4; ++mf) {
            int row = mf * 16 + (lane & 15);
            a[mf] = *(const f16x8*)(lds_h + ((row * 512 + colb) ^ ((row & 7) << 4)));
        }
#pragma unroll
        for (int g = 0; g < 3; ++g) {
            const int tgt = (g == 2) ? 3 : g;
#pragma unroll
            for (int nf = 0; nf < 2; ++nf) {
                f16x8 b = *(const f16x8*)(PhhW + (size_t)g * (256 * 256)
                                          + ks * 8192 + nf * 512 + le8);
#pragma unroll
                for (int mf = 0; mf < 4; ++mf)
                    acc[tgt][mf][nf] = __builtin_amdgcn_mfma_f32_16x16x32_f16(a[mf], b, acc[tgt][mf][nf], 0, 0, 0);
            }
        }
    }
    // epilogue (h from lds_h; in-place global write is race-free)
#pragma unroll
    for (int nf = 0; nf < 2; ++nf) {
        const int j = cb + nf * 16 + (lane & 15);
        const float b_r = bih[j] + bhh[j];
        const float b_z = bih[256 + j] + bhh[256 + j];
        const float b_i = bih[512 + j];
        const float b_h = bhh[512 + j];
#pragma unroll
        for (int mf = 0; mf < 4; ++mf) {
            const int rloc = mf * 16 + ((lane >> 4) << 2);
#pragma unroll
            for (int reg = 0; reg < 4; ++reg) {
                const int rr = rloc + reg;
                float r = sigmoidf_(acc[0][mf][nf][reg] + b_r);
                float z = sigmoidf_(acc[1][mf][nf][reg] + b_z);
                float nn = tanhf_(acc[2][mf][nf][reg] + b_i + r * (acc[3][mf][nf][reg] + b_h));
                float h = (float)*(const f16*)(lds_h + ((rr * 512 + j * 2) ^ ((rr & 7) << 4)));
                uef[(size_t)(e0 + rr) * 256 + j] = (f16)(nn + z * (h - nn));
            }
        }
    }
}

// ---------------------------------------------------------------------------
// Fused node GRU, IN-PLACE on unf (fp32 state); also refreshes f16 shadow.
// Block: 64 nodes x 256 cols, 1024 threads, 16 waves.
// ---------------------------------------------------------------------------
__global__ __launch_bounds__(1024) void node_gru(
        const float* __restrict__ agg, float* __restrict__ unf,
        f16* __restrict__ unf16,
        const f16* __restrict__ Pih, const f16* __restrict__ Phh,
        const float* __restrict__ bih, const float* __restrict__ bhh, int M) {
    const int lane = threadIdx.x & 63, wave = threadIdx.x >> 6;
    const int wm = wave & 1, wn = wave >> 1;
    const int rb = blockIdx.x * 64 + wm * 32;
    const int cb = wn * 32;
    const int nb0 = wn * 2;
    const int kl = (lane >> 4) << 3;
    int r0 = rb + (lane & 15), r1 = r0 + 16;
    int rc0 = r0 < M ? r0 : M - 1;
    int rc1 = r1 < M ? r1 : M - 1;
    f32x4 acc[4][2][2] = {};
#pragma unroll
    for (int ks = 0; ks < 8; ++ks) {
        const float* p0 = agg + (size_t)rc0 * 256 + ks * 32 + kl;
        const float* p1 = agg + (size_t)rc1 * 256 + ks * 32 + kl;
        f16x8 a0, a1;
#pragma unroll
        for (int i = 0; i < 8; ++i) { a0[i] = (f16)p0[i]; a1[i] = (f16)p1[i]; }
#pragma unroll
        for (int g = 0; g < 3; ++g) {
            const f16* Pg = Pih + (size_t)g * (256 * 256);
#pragma unroll
            for (int nf = 0; nf < 2; ++nf) {
                f16x8 b = *(const f16x8*)(Pg + (((size_t)ks * 16 + nb0 + nf) * 64 + lane) * 8);
                acc[g][0][nf] = __builtin_amdgcn_mfma_f32_16x16x32_f16(a0, b, acc[g][0][nf], 0, 0, 0);
                acc[g][1][nf] = __builtin_amdgcn_mfma_f32_16x16x32_f16(a1, b, acc[g][1][nf], 0, 0, 0);
            }
        }
    }
#pragma unroll
    for (int ks = 0; ks < 8; ++ks) {
        const float* p0 = unf + (size_t)rc0 * 256 + ks * 32 + kl;
        const float* p1 = unf + (size_t)rc1 * 256 + ks * 32 + kl;
        f16x8 a0, a1;
#pragma unroll
        for (int i = 0; i < 8; ++i) { a0[i] = (f16)p0[i]; a1[i] = (f16)p1[i]; }
#pragma unroll
        for (int g = 0; g < 3; ++g) {
            const f16* Pg = Phh + (size_t)g * (256 * 256);
            const int tgt = (g == 2) ? 3 : g;
#pragma unroll
            for (int nf = 0; nf < 2; ++nf) {
                f16x8 b = *(const f16x8*)(Pg + (((size_t)ks * 16 + nb0 + nf) * 64 + lane) * 8);
                acc[tgt][0][nf] = __builtin_amdgcn_mfma_f32_16x16x32_f16(a0, b, acc[tgt][0][nf], 0, 0, 0);
                acc[tgt][1][nf] = __builtin_amdgcn_mfma_f32_16x16x32_f16(a1, b, acc[tgt][1][nf], 0, 0, 0);
            }
        }
    }
    __syncthreads();
#pragma unroll
    for (int mf = 0; mf < 2; ++mf) {
        const int row = rb + mf * 16 + ((lane >> 4) << 2);
#pragma unroll
        for (int nf = 0; nf < 2; ++nf) {
            const int j = cb + nf * 16 + (lane & 15);
            const float b_r = bih[j] + bhh[j];
            const float b_z = bih[256 + j] + bhh[256 + j];
            const float b_i = bih[512 + j];
            const float b_h = bhh[512 + j];
#pragma unroll
            for (int reg = 0; reg < 4; ++reg) {
                const int rr = row + reg;
                if (rr < M) {
                    float r = sigmoidf_(acc[0][mf][nf][reg] + b_r);
                    float z = sigmoidf_(acc[1][mf][nf][reg] + b_z);
                    float nn = tanhf_(acc[2][mf][nf][reg] + b_i + r * (acc[3][mf][nf][reg] + b_h));
                    float h = unf[(size_t)rr * 256 + j];     // own region only
                    float v = nn + z * (h - nn);
                    unf[(size_t)rr * 256 + j] = v;
                    unf16[(size_t)rr * 256 + j] = (f16)v;
                }
            }
        }
    }
}

// ---------------------------------------------------------------------------
// CSR build + aggregation (fp32 accumulate, fp32 store)
// ---------------------------------------------------------------------------
__global__ void hist_k(const int* __restrict__ dst, int* __restrict__ cnt, int E) {
    int e = blockIdx.x * 256 + threadIdx.x;
    if (e < E) atomicAdd(&cnt[dst[e]], 1);
}

__global__ void scan_k(const int* __restrict__ cnt, int* __restrict__ rowptr, int n) {
    __shared__ int s[1024];
    __shared__ int carry_s;
    if (threadIdx.x == 0) { carry_s = 0; rowptr[0] = 0; }
    __syncthreads();
    for (int base = 0; base < n; base += 1024) {
        int i = base + (int)threadIdx.x;
        int v = (i < n) ? cnt[i] : 0;
        s[threadIdx.x] = v;
        __syncthreads();
        for (int off = 1; off < 1024; off <<= 1) {
            int tv = (threadIdx.x >= (unsigned)off) ? s[threadIdx.x - off] : 0;
            __syncthreads();
            s[threadIdx.x] += tv;
            __syncthreads();
        }
        if (i < n) rowptr[i + 1] = carry_s + s[threadIdx.x];
        __syncthreads();
        if (threadIdx.x == 0) carry_s += s[1023];
        __syncthreads();
    }
}

__global__ void scatter_k(const int* __restrict__ dst, const int* __restrict__ rowptr,
                          int* __restrict__ cnt2, int* __restrict__ eidx, int E) {
    int e = blockIdx.x * 256 + threadIdx.x;
    if (e < E) {
        int d = dst[e];
        int p = rowptr[d] + atomicAdd(&cnt2[d], 1);
        eidx[p] = e;
    }
}

__global__ void aggregate_k(const f16* __restrict__ uef, const int* __restrict__ eidx,
                            const int* __restrict__ rowptr, float* __restrict__ agg) {
    const int n = blockIdx.x;
    const int c = threadIdx.x;  // 256 threads, one column each
    const int b = rowptr[n], e = rowptr[n + 1];
    float acc = 0.f;
    for (int j = b; j < e; ++j) acc += (float)uef[(size_t)eidx[j] * 256 + c];
    agg[(size_t)n * 256 + c] = acc;
}

// ---------------------------------------------------------------------------
extern "C" void kernel_launch(void* const* d_in, const int* in_sizes, int n_in,
                              void* d_out, int out_size, void* d_ws, size_t ws_size,
                              hipStream_t stream) {
    (void)in_sizes; (void)n_in; (void)out_size; (void)ws_size;
    const float* nf    = (const float*)d_in[0];
    const float* ef    = (const float*)d_in[1];
    const int*   src   = (const int*)d_in[2];
    const int*   dst   = (const int*)d_in[3];
    const float* Wne   = (const float*)d_in[4];
    const float* bne   = (const float*)d_in[5];
    const float* Wee   = (const float*)d_in[6];
    const float* bee   = (const float*)d_in[7];
    const float* Wih_e = (const float*)d_in[8];
    const float* Whh_e = (const float*)d_in[9];
    const float* bih_e = (const float*)d_in[10];
    const float* bhh_e = (const float*)d_in[11];
    const float* Wih_n = (const float*)d_in[12];
    const float* Whh_n = (const float*)d_in[13];
    const float* bih_n = (const float*)d_in[14];
    const float* bhh_n = (const float*)d_in[15];
    const float* Wnd   = (const float*)d_in[16];
    const float* bnd   = (const float*)d_in[17];
    const float* Wed   = (const float*)d_in[18];
    const float* bed   = (const float*)d_in[19];

    char* ws = (char*)d_ws;
    size_t off = 0;
    auto alloc = [&](size_t bytes) -> void* {
        void* p = ws + off;
        off += (bytes + 255) & ~(size_t)255;
        return p;
    };
    // total ~197 MB (well under the ~347 MB proven-working bound)
    f16*   uefA  = (f16*)alloc((size_t)NEDGES * 256 * 2);      // 163.8 MB
    float* unfA  = (float*)alloc((size_t)NNODES * 256 * 4);    // 10.2 MB
    f16*   unf16 = (f16*)alloc((size_t)NNODES * 256 * 2);      // 5.1 MB
    float* agg   = (float*)alloc((size_t)NNODES * 256 * 4);    // 10.2 MB
    f16*   Pih_e = (f16*)alloc((size_t)3 * 512 * 256 * 2);
    f16*   Phh_e = (f16*)alloc((size_t)3 * 256 * 256 * 2);
    f16*   Pih_n = (f16*)alloc((size_t)3 * 256 * 256 * 2);
    f16*   Phh_n = (f16*)alloc((size_t)3 * 256 * 256 * 2);
    f16*   Pne   = (f16*)alloc((size_t)256 * 128 * 2);
    f16*   Pee   = (f16*)alloc((size_t)256 * 64 * 2);
    f16*   Pnd   = (f16*)alloc((size_t)128 * 256 * 2);
    f16*   Ped   = (f16*)alloc((size_t)64 * 256 * 2);
    int* cnt    = (int*)alloc((size_t)NNODES * 4);
    int* cnt2   = (int*)alloc((size_t)NNODES * 4);
    int* rowptr = (int*)alloc((size_t)(NNODES + 1) * 4);
    int* eidx   = (int*)alloc((size_t)NEDGES * 4);

    hipMemsetAsync(cnt, 0, (size_t)NNODES * 4, stream);
    hipMemsetAsync(cnt2, 0, (size_t)NNODES * 4, stream);

    // pack weights
    for (int g = 0; g < 3; ++g) {
        pack_b<<<(256 * 512 + 255) / 256, 256, 0, stream>>>(Wih_e + (size_t)g * 256 * 512,
                                                            Pih_e + (size_t)g * 512 * 256, 256, 512);
        pack_b<<<(256 * 256 + 255) / 256, 256, 0, stream>>>(Whh_e + (size_t)g * 256 * 256,
                                                            Phh_e + (size_t)g * 256 * 256, 256, 256);
        pack_b<<<(256 * 256 + 255) / 256, 256, 0, stream>>>(Wih_n + (size_t)g * 256 * 256,
                                                            Pih_n + (size_t)g * 256 * 256, 256, 256);
        pack_b<<<(256 * 256 + 255) / 256, 256, 0, stream>>>(Whh_n + (size_t)g * 256 * 256,
                                                            Phh_n + (size_t)g * 256 * 256, 256, 256);
    }
    pack_b<<<(256 * 128 + 255) / 256, 256, 0, stream>>>(Wne, Pne, 256, 128);
    pack_b<<<(256 * 64 + 255) / 256, 256, 0, stream>>>(Wee, Pee, 256, 64);
    pack_b<<<(128 * 256 + 255) / 256, 256, 0, stream>>>(Wnd, Pnd, 128, 256);
    pack_b<<<(64 * 256 + 255) / 256, 256, 0, stream>>>(Wed, Ped, 64, 256);

    // CSR by dst
    hist_k<<<(NEDGES + 255) / 256, 256, 0, stream>>>(dst, cnt, NEDGES);
    scan_k<<<1, 1024, 0, stream>>>(cnt, rowptr, NNODES);
    scatter_k<<<(NEDGES + 255) / 256, 256, 0, stream>>>(dst, rowptr, cnt2, eidx, NEDGES);

    // encode (node encoder -> fp32 unf + f16 shadow; edge encoder -> f16 uef)
    gemm_bias<0, 2><<<dim3(157, 4), 256, 0, stream>>>(nf, Pne, bne, unfA, unf16, NNODES, 256, 128);
    gemm_bias<0, 1><<<dim3(5000, 4), 256, 0, stream>>>(ef, Pee, bee, uefA, nullptr, NEDGES, 256, 64);

    // message passing (both GRUs in-place)
    for (int it = 0; it < 3; ++it) {
        edge_gru<<<5000, 512, 0, stream>>>(unf16, uefA, src, dst, Pih_e, Phh_e, bih_e, bhh_e);
        aggregate_k<<<NNODES, 256, 0, stream>>>(uefA, eidx, rowptr, agg);
        node_gru<<<157, 1024, 0, stream>>>(agg, unfA, unf16, Pih_n, Phh_n, bih_n, bhh_n, NNODES);
    }

    // decode (node from fp32 unf; edge from f16 uef)
    gemm_bias<0, 0><<<dim3(157, 2), 256, 0, stream>>>(unfA, Pnd, bnd, d_out, nullptr, NNODES, 128, 256);
    gemm_bias<1, 0><<<dim3(5000, 1), 256, 0, stream>>>(uefA, Ped, bed,
                                                       (float*)d_out + (size_t)NNODES * 128, nullptr,
                                                       NEDGES, 64, 256);
}

// Round 9
// 2593.846 us; speedup vs baseline: 4.1832x; 1.4856x over previous
//
#include <hip/hip_runtime.h>
#include <hip/hip_bf16.h>
#include <cstddef>

typedef _Float16 f16;
typedef f16 f16x8 __attribute__((ext_vector_type(8)));
typedef float f32x4 __attribute__((ext_vector_type(4)));

#define NNODES 10000
#define NEDGES 320000

// ---------------------------------------------------------------------------
// Pack W [Nout][K] (fp32, row-major) into MFMA-B fragment-linear fp16:
// P[((ks*NB + nb)*64 + lane)*8 + i] = W[nb*16 + (lane&15)][ks*32 + 8*(lane>>4) + i]
// ---------------------------------------------------------------------------
__global__ void pack_b(const float* __restrict__ W, f16* __restrict__ P,
                       int Nout, int K) {
    int idx = blockIdx.x * 256 + threadIdx.x;
    int total = Nout * K;
    if (idx >= total) return;
    int i = idx & 7;
    int l = (idx >> 3) & 63;
    int rest = idx >> 9;
    int NB = Nout >> 4;
    int nb = rest % NB;
    int ks = rest / NB;
    int k = ks * 32 + ((l >> 4) << 3) + i;
    int n = nb * 16 + (l & 15);
    P[idx] = (f16)W[(size_t)n * K + k];
}

// ---------------------------------------------------------------------------
// Generic C = A @ W^T + bias. AMODE: 0 = fp32 A (convert), 1 = f16 A.
// OMODE: 0 = f32 out, 1 = f16 out, 2 = f32 out + f16 shadow copy (C2).
// ---------------------------------------------------------------------------
template <int AMODE, int OMODE>
__global__ void gemm_bias(const void* __restrict__ A_, const f16* __restrict__ P,
                          const float* __restrict__ bias, void* __restrict__ C_,
                          f16* __restrict__ C2, int M, int Nout, int K) {
    const int lane = threadIdx.x & 63, wave = threadIdx.x >> 6;
    const int wm = wave >> 1, wn = wave & 1;
    const int rb = blockIdx.x * 64 + wm * 32;
    const int cb = blockIdx.y * 64 + wn * 32;
    const int NB = Nout >> 4;
    const int kl = (lane >> 4) << 3;
    int r0 = rb + (lane & 15);
    int r1 = r0 + 16;
    int rc0 = r0 < M ? r0 : M - 1;
    int rc1 = r1 < M ? r1 : M - 1;
    f32x4 acc[2][2] = {};
    for (int ks = 0; ks < (K >> 5); ++ks) {
        int kb = ks * 32 + kl;
        f16x8 a0, a1;
        if constexpr (AMODE == 1) {
            const f16* A = (const f16*)A_;
            a0 = *(const f16x8*)(A + (size_t)rc0 * K + kb);
            a1 = *(const f16x8*)(A + (size_t)rc1 * K + kb);
        } else {
            const float* A = (const float*)A_;
            const float* p0 = A + (size_t)rc0 * K + kb;
            const float* p1 = A + (size_t)rc1 * K + kb;
#pragma unroll
            for (int i = 0; i < 8; ++i) { a0[i] = (f16)p0[i]; a1[i] = (f16)p1[i]; }
        }
#pragma unroll
        for (int nf = 0; nf < 2; ++nf) {
            int nb = (cb >> 4) + nf;
            f16x8 b = *(const f16x8*)(P + (((size_t)ks * NB + nb) * 64 + lane) * 8);
            acc[0][nf] = __builtin_amdgcn_mfma_f32_16x16x32_f16(a0, b, acc[0][nf], 0, 0, 0);
            acc[1][nf] = __builtin_amdgcn_mfma_f32_16x16x32_f16(a1, b, acc[1][nf], 0, 0, 0);
        }
    }
#pragma unroll
    for (int mf = 0; mf < 2; ++mf)
#pragma unroll
        for (int nf = 0; nf < 2; ++nf)
#pragma unroll
            for (int reg = 0; reg < 4; ++reg) {
                int row = rb + mf * 16 + ((lane >> 4) << 2) + reg;
                int col = cb + nf * 16 + (lane & 15);
                if (row < M) {
                    float v = acc[mf][nf][reg] + bias[col];
                    if constexpr (OMODE == 0) {
                        ((float*)C_)[(size_t)row * Nout + col] = v;
                    } else if constexpr (OMODE == 1) {
                        ((f16*)C_)[(size_t)row * Nout + col] = (f16)v;
                    } else {
                        ((float*)C_)[(size_t)row * Nout + col] = v;
                        C2[(size_t)row * Nout + col] = (f16)v;
                    }
                }
            }
}

// fast activations; tail-safe without clamps (inf handled by rcp -> 0)
__device__ inline float sigmoidf_(float x) {
    return __fdividef(1.f, 1.f + __expf(-x));
}
__device__ inline float tanhf_(float x) {
    float t = __expf(2.f * x);           // inf for large x is fine
    return 1.f - __fdividef(2.f, t + 1.f);
}

// ---------------------------------------------------------------------------
// Fused edge GRU v5, IN-PLACE on uef. Block: 64 edges x 256 cols, 1024 thr =
// 16 waves. Wave tile: 64 edges x 16 cols (mf=4, nf=1) -> acc[4][4] = 64 regs,
// total ~120 <= 128 => 16 waves/CU = 4 waves/SIMD (2x round-5 occupancy) while
// keeping 4 MFMA per B-load (B-L2 traffic unchanged at ~1.15 MB/block).
// xe (128 gathered unf16 rows) + uef rows staged once into swizzled LDS; all
// global uef reads happen in staging, so post-barrier in-place writes are safe.
// acc sets: 0 = ir+hr, 1 = iz+hz, 2 = inn, 3 = hn
// ---------------------------------------------------------------------------
__global__ __launch_bounds__(1024, 4) void edge_gru(
        const f16* __restrict__ unf16, f16* __restrict__ uef,
        const int* __restrict__ src, const int* __restrict__ dst,
        const f16* __restrict__ Pih, const f16* __restrict__ Phh,
        const float* __restrict__ bih, const float* __restrict__ bhh) {
    __shared__ int s_idx[128];
    __shared__ char lds_x[128 * 512];   // xe tile: 128 rows x 512 B, swizzled
    __shared__ char lds_h[64 * 512];    // uef tile: 64 rows x 512 B, swizzled
    const int t = threadIdx.x;
    const int e0 = blockIdx.x * 64;
    if (t < 64) s_idx[t] = src[e0 + t];
    else if (t < 128) s_idx[t] = dst[e0 + t - 64];
    __syncthreads();
    // stage xe: 128 rows x 32 segs(16B) = 4096 segs / 1024 thr = 4 iters
#pragma unroll
    for (int i = 0; i < 4; ++i) {
        int s = t + i * 1024;
        int row = s >> 5, seg = s & 31;
        f16x8 v = *(const f16x8*)(unf16 + (size_t)s_idx[row] * 256 + seg * 8);
        *(f16x8*)(lds_x + ((row * 512 + seg * 16) ^ ((row & 7) << 4))) = v;
    }
    // stage uef: 64 rows x 32 segs = 2048 / 1024 = 2 iters
#pragma unroll
    for (int i = 0; i < 2; ++i) {
        int s = t + i * 1024;
        int row = s >> 5, seg = s & 31;
        f16x8 v = *(const f16x8*)(uef + (size_t)(e0 + row) * 256 + seg * 8);
        *(f16x8*)(lds_h + ((row * 512 + seg * 16) ^ ((row & 7) << 4))) = v;
    }
    __syncthreads();
    const int lane = t & 63;
    const int wn = t >> 6;               // 16 waves, one 16-col group each
    const int klb = (lane >> 4) << 4;    // byte offset of lane's k-slice
    f32x4 acc[4][4] = {};                // [gateset][mf]
    // phase 1: xe @ Wih^T (K = 512; rows 0..63 = src half, 64..127 = dst half)
#pragma unroll
    for (int ks = 0; ks < 16; ++ks) {
        const int colb = (ks & 7) * 64 + klb;
        const int rbase = (ks < 8) ? 0 : 64;
        f16x8 a[4];
#pragma unroll
        for (int mf = 0; mf < 4; ++mf) {
            int row = rbase + mf * 16 + (lane & 15);
            a[mf] = *(const f16x8*)(lds_x + ((row * 512 + colb) ^ ((row & 7) << 4)));
        }
#pragma unroll
        for (int g = 0; g < 3; ++g) {
            const f16* Pg = Pih + (size_t)g * (512 * 256);
            f16x8 b = *(const f16x8*)(Pg + (((size_t)ks * 16 + wn) * 64 + lane) * 8);
#pragma unroll
            for (int mf = 0; mf < 4; ++mf)
                acc[g][mf] = __builtin_amdgcn_mfma_f32_16x16x32_f16(a[mf], b, acc[g][mf], 0, 0, 0);
        }
    }
    // phase 2: h @ Whh^T (K = 256, A = staged uef tile)
#pragma unroll
    for (int ks = 0; ks < 8; ++ks) {
        const int colb = ks * 64 + klb;
        f16x8 a[4];
#pragma unroll
        for (int mf = 0; mf < 4; ++mf) {
            int row = mf * 16 + (lane & 15);
            a[mf] = *(const f16x8*)(lds_h + ((row * 512 + colb) ^ ((row & 7) << 4)));
        }
#pragma unroll
        for (int g = 0; g < 3; ++g) {
            const int tgt = (g == 2) ? 3 : g;
            const f16* Pg = Phh + (size_t)g * (256 * 256);
            f16x8 b = *(const f16x8*)(Pg + (((size_t)ks * 16 + wn) * 64 + lane) * 8);
#pragma unroll
            for (int mf = 0; mf < 4; ++mf)
                acc[tgt][mf] = __builtin_amdgcn_mfma_f32_16x16x32_f16(a[mf], b, acc[tgt][mf], 0, 0, 0);
        }
    }
    // epilogue (h from lds_h; in-place global write is race-free)
    {
        const int j = wn * 16 + (lane & 15);
        const float b_r = bih[j] + bhh[j];
        const float b_z = bih[256 + j] + bhh[256 + j];
        const float b_i = bih[512 + j];
        const float b_h = bhh[512 + j];
#pragma unroll
        for (int mf = 0; mf < 4; ++mf) {
            const int rloc = mf * 16 + ((lane >> 4) << 2);
#pragma unroll
            for (int reg = 0; reg < 4; ++reg) {
                const int rr = rloc + reg;
                float r = sigmoidf_(acc[0][mf][reg] + b_r);
                float z = sigmoidf_(acc[1][mf][reg] + b_z);
                float nn = tanhf_(acc[2][mf][reg] + b_i + r * (acc[3][mf][reg] + b_h));
                float h = (float)*(const f16*)(lds_h + ((rr * 512 + j * 2) ^ ((rr & 7) << 4)));
                uef[(size_t)(e0 + rr) * 256 + j] = (f16)(nn + z * (h - nn));
            }
        }
    }
}

// ---------------------------------------------------------------------------
// Fused node GRU, IN-PLACE on unf (fp32 state); also refreshes f16 shadow.
// Block: 64 nodes x 256 cols, 1024 threads, 16 waves.
// ---------------------------------------------------------------------------
__global__ __launch_bounds__(1024) void node_gru(
        const float* __restrict__ agg, float* __restrict__ unf,
        f16* __restrict__ unf16,
        const f16* __restrict__ Pih, const f16* __restrict__ Phh,
        const float* __restrict__ bih, const float* __restrict__ bhh, int M) {
    const int lane = threadIdx.x & 63, wave = threadIdx.x >> 6;
    const int wm = wave & 1, wn = wave >> 1;
    const int rb = blockIdx.x * 64 + wm * 32;
    const int cb = wn * 32;
    const int nb0 = wn * 2;
    const int kl = (lane >> 4) << 3;
    int r0 = rb + (lane & 15), r1 = r0 + 16;
    int rc0 = r0 < M ? r0 : M - 1;
    int rc1 = r1 < M ? r1 : M - 1;
    f32x4 acc[4][2][2] = {};
#pragma unroll
    for (int ks = 0; ks < 8; ++ks) {
        const float* p0 = agg + (size_t)rc0 * 256 + ks * 32 + kl;
        const float* p1 = agg + (size_t)rc1 * 256 + ks * 32 + kl;
        f16x8 a0, a1;
#pragma unroll
        for (int i = 0; i < 8; ++i) { a0[i] = (f16)p0[i]; a1[i] = (f16)p1[i]; }
#pragma unroll
        for (int g = 0; g < 3; ++g) {
            const f16* Pg = Pih + (size_t)g * (256 * 256);
#pragma unroll
            for (int nf = 0; nf < 2; ++nf) {
                f16x8 b = *(const f16x8*)(Pg + (((size_t)ks * 16 + nb0 + nf) * 64 + lane) * 8);
                acc[g][0][nf] = __builtin_amdgcn_mfma_f32_16x16x32_f16(a0, b, acc[g][0][nf], 0, 0, 0);
                acc[g][1][nf] = __builtin_amdgcn_mfma_f32_16x16x32_f16(a1, b, acc[g][1][nf], 0, 0, 0);
            }
        }
    }
#pragma unroll
    for (int ks = 0; ks < 8; ++ks) {
        const float* p0 = unf + (size_t)rc0 * 256 + ks * 32 + kl;
        const float* p1 = unf + (size_t)rc1 * 256 + ks * 32 + kl;
        f16x8 a0, a1;
#pragma unroll
        for (int i = 0; i < 8; ++i) { a0[i] = (f16)p0[i]; a1[i] = (f16)p1[i]; }
#pragma unroll
        for (int g = 0; g < 3; ++g) {
            const f16* Pg = Phh + (size_t)g * (256 * 256);
            const int tgt = (g == 2) ? 3 : g;
#pragma unroll
            for (int nf = 0; nf < 2; ++nf) {
                f16x8 b = *(const f16x8*)(Pg + (((size_t)ks * 16 + nb0 + nf) * 64 + lane) * 8);
                acc[tgt][0][nf] = __builtin_amdgcn_mfma_f32_16x16x32_f16(a0, b, acc[tgt][0][nf], 0, 0, 0);
                acc[tgt][1][nf] = __builtin_amdgcn_mfma_f32_16x16x32_f16(a1, b, acc[tgt][1][nf], 0, 0, 0);
            }
        }
    }
    __syncthreads();
#pragma unroll
    for (int mf = 0; mf < 2; ++mf) {
        const int row = rb + mf * 16 + ((lane >> 4) << 2);
#pragma unroll
        for (int nf = 0; nf < 2; ++nf) {
            const int j = cb + nf * 16 + (lane & 15);
            const float b_r = bih[j] + bhh[j];
            const float b_z = bih[256 + j] + bhh[256 + j];
            const float b_i = bih[512 + j];
            const float b_h = bhh[512 + j];
#pragma unroll
            for (int reg = 0; reg < 4; ++reg) {
                const int rr = row + reg;
                if (rr < M) {
                    float r = sigmoidf_(acc[0][mf][nf][reg] + b_r);
                    float z = sigmoidf_(acc[1][mf][nf][reg] + b_z);
                    float nn = tanhf_(acc[2][mf][nf][reg] + b_i + r * (acc[3][mf][nf][reg] + b_h));
                    float h = unf[(size_t)rr * 256 + j];     // own region only
                    float v = nn + z * (h - nn);
                    unf[(size_t)rr * 256 + j] = v;
                    unf16[(size_t)rr * 256 + j] = (f16)v;
                }
            }
        }
    }
}

// ---------------------------------------------------------------------------
// CSR build + aggregation (fp32 accumulate, fp32 store)
// ---------------------------------------------------------------------------
__global__ void hist_k(const int* __restrict__ dst, int* __restrict__ cnt, int E) {
    int e = blockIdx.x * 256 + threadIdx.x;
    if (e < E) atomicAdd(&cnt[dst[e]], 1);
}

__global__ void scan_k(const int* __restrict__ cnt, int* __restrict__ rowptr, int n) {
    __shared__ int s[1024];
    __shared__ int carry_s;
    if (threadIdx.x == 0) { carry_s = 0; rowptr[0] = 0; }
    __syncthreads();
    for (int base = 0; base < n; base += 1024) {
        int i = base + (int)threadIdx.x;
        int v = (i < n) ? cnt[i] : 0;
        s[threadIdx.x] = v;
        __syncthreads();
        for (int off = 1; off < 1024; off <<= 1) {
            int tv = (threadIdx.x >= (unsigned)off) ? s[threadIdx.x - off] : 0;
            __syncthreads();
            s[threadIdx.x] += tv;
            __syncthreads();
        }
        if (i < n) rowptr[i + 1] = carry_s + s[threadIdx.x];
        __syncthreads();
        if (threadIdx.x == 0) carry_s += s[1023];
        __syncthreads();
    }
}

__global__ void scatter_k(const int* __restrict__ dst, const int* __restrict__ rowptr,
                          int* __restrict__ cnt2, int* __restrict__ eidx, int E) {
    int e = blockIdx.x * 256 + threadIdx.x;
    if (e < E) {
        int d = dst[e];
        int p = rowptr[d] + atomicAdd(&cnt2[d], 1);
        eidx[p] = e;
    }
}

__global__ void aggregate_k(const f16* __restrict__ uef, const int* __restrict__ eidx,
                            const int* __restrict__ rowptr, float* __restrict__ agg) {
    const int n = blockIdx.x;
    const int c = threadIdx.x;  // 256 threads, one column each
    const int b = rowptr[n], e = rowptr[n + 1];
    float acc = 0.f;
    for (int j = b; j < e; ++j) acc += (float)uef[(size_t)eidx[j] * 256 + c];
    agg[(size_t)n * 256 + c] = acc;
}

// ---------------------------------------------------------------------------
extern "C" void kernel_launch(void* const* d_in, const int* in_sizes, int n_in,
                              void* d_out, int out_size, void* d_ws, size_t ws_size,
                              hipStream_t stream) {
    (void)in_sizes; (void)n_in; (void)out_size; (void)ws_size;
    const float* nf    = (const float*)d_in[0];
    const float* ef    = (const float*)d_in[1];
    const int*   src   = (const int*)d_in[2];
    const int*   dst   = (const int*)d_in[3];
    const float* Wne   = (const float*)d_in[4];
    const float* bne   = (const float*)d_in[5];
    const float* Wee   = (const float*)d_in[6];
    const float* bee   = (const float*)d_in[7];
    const float* Wih_e = (const float*)d_in[8];
    const float* Whh_e = (const float*)d_in[9];
    const float* bih_e = (const float*)d_in[10];
    const float* bhh_e = (const float*)d_in[11];
    const float* Wih_n = (const float*)d_in[12];
    const float* Whh_n = (const float*)d_in[13];
    const float* bih_n = (const float*)d_in[14];
    const float* bhh_n = (const float*)d_in[15];
    const float* Wnd   = (const float*)d_in[16];
    const float* bnd   = (const float*)d_in[17];
    const float* Wed   = (const float*)d_in[18];
    const float* bed   = (const float*)d_in[19];

    char* ws = (char*)d_ws;
    size_t off = 0;
    auto alloc = [&](size_t bytes) -> void* {
        void* p = ws + off;
        off += (bytes + 255) & ~(size_t)255;
        return p;
    };
    // total ~197 MB (well under the ~347 MB proven-working bound)
    f16*   uefA  = (f16*)alloc((size_t)NEDGES * 256 * 2);      // 163.8 MB
    float* unfA  = (float*)alloc((size_t)NNODES * 256 * 4);    // 10.2 MB
    f16*   unf16 = (f16*)alloc((size_t)NNODES * 256 * 2);      // 5.1 MB
    float* agg   = (float*)alloc((size_t)NNODES * 256 * 4);    // 10.2 MB
    f16*   Pih_e = (f16*)alloc((size_t)3 * 512 * 256 * 2);
    f16*   Phh_e = (f16*)alloc((size_t)3 * 256 * 256 * 2);
    f16*   Pih_n = (f16*)alloc((size_t)3 * 256 * 256 * 2);
    f16*   Phh_n = (f16*)alloc((size_t)3 * 256 * 256 * 2);
    f16*   Pne   = (f16*)alloc((size_t)256 * 128 * 2);
    f16*   Pee   = (f16*)alloc((size_t)256 * 64 * 2);
    f16*   Pnd   = (f16*)alloc((size_t)128 * 256 * 2);
    f16*   Ped   = (f16*)alloc((size_t)64 * 256 * 2);
    int* cnt    = (int*)alloc((size_t)NNODES * 4);
    int* cnt2   = (int*)alloc((size_t)NNODES * 4);
    int* rowptr = (int*)alloc((size_t)(NNODES + 1) * 4);
    int* eidx   = (int*)alloc((size_t)NEDGES * 4);

    hipMemsetAsync(cnt, 0, (size_t)NNODES * 4, stream);
    hipMemsetAsync(cnt2, 0, (size_t)NNODES * 4, stream);

    // pack weights
    for (int g = 0; g < 3; ++g) {
        pack_b<<<(256 * 512 + 255) / 256, 256, 0, stream>>>(Wih_e + (size_t)g * 256 * 512,
                                                            Pih_e + (size_t)g * 512 * 256, 256, 512);
        pack_b<<<(256 * 256 + 255) / 256, 256, 0, stream>>>(Whh_e + (size_t)g * 256 * 256,
                                                            Phh_e + (size_t)g * 256 * 256, 256, 256);
        pack_b<<<(256 * 256 + 255) / 256, 256, 0, stream>>>(Wih_n + (size_t)g * 256 * 256,
                                                            Pih_n + (size_t)g * 256 * 256, 256, 256);
        pack_b<<<(256 * 256 + 255) / 256, 256, 0, stream>>>(Whh_n + (size_t)g * 256 * 256,
                                                            Phh_n + (size_t)g * 256 * 256, 256, 256);
    }
    pack_b<<<(256 * 128 + 255) / 256, 256, 0, stream>>>(Wne, Pne, 256, 128);
    pack_b<<<(256 * 64 + 255) / 256, 256, 0, stream>>>(Wee, Pee, 256, 64);
    pack_b<<<(128 * 256 + 255) / 256, 256, 0, stream>>>(Wnd, Pnd, 128, 256);
    pack_b<<<(64 * 256 + 255) / 256, 256, 0, stream>>>(Wed, Ped, 64, 256);

    // CSR by dst
    hist_k<<<(NEDGES + 255) / 256, 256, 0, stream>>>(dst, cnt, NEDGES);
    scan_k<<<1, 1024, 0, stream>>>(cnt, rowptr, NNODES);
    scatter_k<<<(NEDGES + 255) / 256, 256, 0, stream>>>(dst, rowptr, cnt2, eidx, NEDGES);

    // encode (node encoder -> fp32 unf + f16 shadow; edge encoder -> f16 uef)
    gemm_bias<0, 2><<<dim3(157, 4), 256, 0, stream>>>(nf, Pne, bne, unfA, unf16, NNODES, 256, 128);
    gemm_bias<0, 1><<<dim3(5000, 4), 256, 0, stream>>>(ef, Pee, bee, uefA, nullptr, NEDGES, 256, 64);

    // message passing (both GRUs in-place)
    for (int it = 0; it < 3; ++it) {
        edge_gru<<<5000, 1024, 0, stream>>>(unf16, uefA, src, dst, Pih_e, Phh_e, bih_e, bhh_e);
        aggregate_k<<<NNODES, 256, 0, stream>>>(uefA, eidx, rowptr, agg);
        node_gru<<<157, 1024, 0, stream>>>(agg, unfA, unf16, Pih_n, Phh_n, bih_n, bhh_n, NNODES);
    }

    // decode (node from fp32 unf; edge from f16 uef)
    gemm_bias<0, 0><<<dim3(157, 2), 256, 0, stream>>>(unfA, Pnd, bnd, d_out, nullptr, NNODES, 128, 256);
    gemm_bias<1, 0><<<dim3(5000, 1), 256, 0, stream>>>(uefA, Ped, bed,
                                                       (float*)d_out + (size_t)NNODES * 128, nullptr,
                                                       NEDGES, 64, 256);
}